// Round 1
// baseline (3205.455 us; speedup 1.0000x reference)
//
#include <hip/hip_runtime.h>
#include <math.h>

#define SEQLEN 2048
#define DIN 2048
#define NH 32
#define NKV 8
#define HD 64
#define DQ (NH*HD)    // 2048
#define DKV (NKV*HD)  // 512

// ---------------------------------------------------------------------------
// Generic fp32 tiled GEMM: C[M,N] = A[M,K] * B[K,N], row-major.
// Requires M % 128 == 0, N % 128 == 0, K % 16 == 0 (true for all our shapes).
// BM=BN=128, BK=16, 256 threads, 8x8 micro-tile per thread.
// ---------------------------------------------------------------------------
__global__ __launch_bounds__(256) void gemm_f32(const float* __restrict__ A,
                                                const float* __restrict__ B,
                                                float* __restrict__ C,
                                                int M, int N, int K) {
    __shared__ float As[16][129];  // [k][m], +1 pad
    __shared__ float Bs[16][128];  // [k][n]
    const int m0 = blockIdx.y * 128;
    const int n0 = blockIdx.x * 128;
    const int t  = threadIdx.x;
    const int ty = t >> 4;   // 0..15
    const int tx = t & 15;   // 0..15

    float acc[8][8];
    #pragma unroll
    for (int i = 0; i < 8; ++i)
        #pragma unroll
        for (int j = 0; j < 8; ++j) acc[i][j] = 0.0f;

    for (int k0 = 0; k0 < K; k0 += 16) {
        // A tile: 128 rows x 16 cols -> As[k][m]
        #pragma unroll
        for (int i = t; i < 2048; i += 256) {
            int r = i >> 4, c = i & 15;
            As[c][r] = A[(size_t)(m0 + r) * K + k0 + c];
        }
        // B tile: 16 rows x 128 cols -> Bs[k][n]
        #pragma unroll
        for (int i = t; i < 2048; i += 256) {
            int r = i >> 7, c = i & 127;
            Bs[r][c] = B[(size_t)(k0 + r) * N + n0 + c];
        }
        __syncthreads();

        #pragma unroll
        for (int k = 0; k < 16; ++k) {
            float a[8], b[8];
            #pragma unroll
            for (int i = 0; i < 8; ++i) a[i] = As[k][ty * 8 + i];
            #pragma unroll
            for (int j = 0; j < 8; ++j) b[j] = Bs[k][tx * 8 + j];
            #pragma unroll
            for (int i = 0; i < 8; ++i)
                #pragma unroll
                for (int j = 0; j < 8; ++j) acc[i][j] += a[i] * b[j];
        }
        __syncthreads();
    }

    // Epilogue: two float4 stores per row of the micro-tile.
    #pragma unroll
    for (int i = 0; i < 8; ++i) {
        float4 v0 = make_float4(acc[i][0], acc[i][1], acc[i][2], acc[i][3]);
        float4 v1 = make_float4(acc[i][4], acc[i][5], acc[i][6], acc[i][7]);
        float* cp = C + (size_t)(m0 + ty * 8 + i) * N + n0 + tx * 8;
        *reinterpret_cast<float4*>(cp)     = v0;
        *reinterpret_cast<float4*>(cp + 4) = v1;
    }
}

// ---------------------------------------------------------------------------
// Fused RMSNorm + RoPE over Q (32 heads) and K (8 heads).
// One wave (64 lanes) handles one (s, head) vector of 64 elements.
// grid = (SEQLEN, 10), block = 256 (4 waves -> 4 heads per block).
// heads 0..31 -> Q with q_norm_w ; heads 32..39 -> K with k_norm_w.
// ---------------------------------------------------------------------------
__global__ __launch_bounds__(256) void norm_rope(float* __restrict__ Q,
                                                 float* __restrict__ Kb,
                                                 const float* __restrict__ cosb,
                                                 const float* __restrict__ sinb,
                                                 const float* __restrict__ qw,
                                                 const float* __restrict__ kw) {
    const int s    = blockIdx.x;
    const int wave = threadIdx.x >> 6;
    const int lane = threadIdx.x & 63;
    const int head = blockIdx.y * 4 + wave;   // 0..39

    float* base;
    const float* w;
    if (head < NH) {
        base = Q + (size_t)s * DQ + head * HD;
        w = qw;
    } else {
        base = Kb + (size_t)s * DKV + (head - NH) * HD;
        w = kw;
    }

    float v  = base[lane];
    float ss = v * v;
    #pragma unroll
    for (int off = 32; off; off >>= 1) ss += __shfl_xor(ss, off);
    float r  = rsqrtf(ss * (1.0f / 64.0f) + 1e-6f);
    float vn = v * r * w[lane];

    // rotate_half via cross-lane xor-32
    float partner = __shfl_xor(vn, 32);
    float sgn = (lane < 32) ? -1.0f : 1.0f;
    float c  = cosb[s * HD + lane];
    float sn = sinb[s * HD + lane];
    base[lane] = vn * c + sgn * partner * sn;
}

// ---------------------------------------------------------------------------
// Causal flash attention, fp32, online softmax.
// grid = (SEQLEN/64, NH), block = 256.
// Each block: 64 query rows of one head. Thread t owns row r=t>>2 and
// 16 dims cb..cb+15 (cb=(t&3)*16) of the output accumulator.
// ---------------------------------------------------------------------------
__global__ __launch_bounds__(256) void attn_f32(const float* __restrict__ Q,
                                                const float* __restrict__ K,
                                                const float* __restrict__ V,
                                                float* __restrict__ Oout) {
    __shared__ float Qs[64][65];
    __shared__ float Ks[64][65];
    __shared__ float Vs[64][64];
    __shared__ float Ss[64][65];

    const int h   = blockIdx.y;
    const int q0  = blockIdx.x * 64;
    const int kvh = h >> 2;            // GQA: 4 query heads per kv head
    const int t   = threadIdx.x;
    const int r   = t >> 2;            // 0..63
    const int cb  = (t & 3) * 16;      // 0,16,32,48

    // Load Q tile
    for (int i = t; i < 4096; i += 256) {
        int rr = i >> 6, d = i & 63;
        Qs[rr][d] = Q[(size_t)(q0 + rr) * DQ + h * HD + d];
    }

    float m_r = -1e30f;
    float l_r = 0.0f;
    float O[16];
    #pragma unroll
    for (int dd = 0; dd < 16; ++dd) O[dd] = 0.0f;

    for (int k0 = 0; k0 <= q0; k0 += 64) {
        __syncthreads();   // protect Ks/Vs from previous iteration's readers
        for (int i = t; i < 4096; i += 256) {
            int rr = i >> 6, d = i & 63;
            Ks[rr][d] = K[(size_t)(k0 + rr) * DKV + kvh * HD + d];
            Vs[rr][d] = V[(size_t)(k0 + rr) * DKV + kvh * HD + d];
        }
        __syncthreads();

        // Scores: 16 keys per thread, full 64-dim dot products
        float acc[16];
        #pragma unroll
        for (int kk = 0; kk < 16; ++kk) acc[kk] = 0.0f;
        for (int d = 0; d < 64; ++d) {
            float qd = Qs[r][d];
            #pragma unroll
            for (int kk = 0; kk < 16; ++kk)
                acc[kk] += qd * Ks[cb + kk][d];
        }
        #pragma unroll
        for (int kk = 0; kk < 16; ++kk) {
            float sc = acc[kk] * 0.125f;           // 1/sqrt(64)
            int kg = k0 + cb + kk;
            if (kg > q0 + r) sc = -1e30f;          // causal mask
            Ss[r][cb + kk] = sc;
        }
        __syncthreads();

        // Online softmax update (replicated across 4 threads of the row)
        float tmax = -1e30f;
        for (int k = 0; k < 64; ++k) tmax = fmaxf(tmax, Ss[r][k]);
        float mnew  = fmaxf(m_r, tmax);
        float alpha = __expf(m_r - mnew);
        l_r *= alpha;
        #pragma unroll
        for (int dd = 0; dd < 16; ++dd) O[dd] *= alpha;
        for (int k = 0; k < 64; ++k) {
            float p = __expf(Ss[r][k] - mnew);
            l_r += p;
            #pragma unroll
            for (int dd = 0; dd < 16; ++dd)
                O[dd] += p * Vs[k][cb + dd];
        }
        m_r = mnew;
    }

    float inv = 1.0f / l_r;
    #pragma unroll
    for (int dd = 0; dd < 16; ++dd)
        Oout[(size_t)(q0 + r) * DQ + h * HD + cb + dd] = O[dd] * inv;
}

// ---------------------------------------------------------------------------
extern "C" void kernel_launch(void* const* d_in, const int* in_sizes, int n_in,
                              void* d_out, int out_size, void* d_ws, size_t ws_size,
                              hipStream_t stream) {
    const float* x    = (const float*)d_in[0];
    const float* cosb = (const float*)d_in[1];
    const float* sinb = (const float*)d_in[2];
    const float* wq   = (const float*)d_in[3];
    const float* wk   = (const float*)d_in[4];
    const float* wv   = (const float*)d_in[5];
    const float* wo   = (const float*)d_in[6];
    const float* qnw  = (const float*)d_in[7];
    const float* knw  = (const float*)d_in[8];
    float* out = (float*)d_out;

    char* ws = (char*)d_ws;
    float* Q    = (float*)(ws);                                     // 16 MB
    float* K    = (float*)(ws + (size_t)SEQLEN * DQ * 4);           //  4 MB
    float* V    = (float*)(ws + (size_t)SEQLEN * DQ * 4
                              + (size_t)SEQLEN * DKV * 4);          //  4 MB
    float* attn = (float*)(ws + (size_t)SEQLEN * DQ * 4
                              + (size_t)SEQLEN * DKV * 4 * 2);      // 16 MB

    // 1) Projections
    gemm_f32<<<dim3(DQ / 128, SEQLEN / 128), 256, 0, stream>>>(x, wq, Q, SEQLEN, DQ, DIN);
    gemm_f32<<<dim3(DKV / 128, SEQLEN / 128), 256, 0, stream>>>(x, wk, K, SEQLEN, DKV, DIN);
    gemm_f32<<<dim3(DKV / 128, SEQLEN / 128), 256, 0, stream>>>(x, wv, V, SEQLEN, DKV, DIN);

    // 2) RMSNorm + RoPE on Q and K
    norm_rope<<<dim3(SEQLEN, 10), 256, 0, stream>>>(Q, K, cosb, sinb, qnw, knw);

    // 3) Causal GQA flash attention
    attn_f32<<<dim3(SEQLEN / 64, NH), 256, 0, stream>>>(Q, K, V, attn);

    // 4) Output projection
    gemm_f32<<<dim3(DQ / 128, SEQLEN / 128), 256, 0, stream>>>(attn, wo, out, SEQLEN, DQ, DIN);
}

// Round 2
// 411.450 us; speedup vs baseline: 7.7906x; 7.7906x over previous
//
#include <hip/hip_runtime.h>
#include <math.h>

#define SEQLEN 2048
#define DIN 2048
#define NH 32
#define NKV 8
#define HD 64
#define DQ (NH*HD)    // 2048
#define DKV (NKV*HD)  // 512

using u16 = unsigned short;
using u32 = unsigned int;
using bf16x8 = __attribute__((ext_vector_type(8))) __bf16;
using f32x4  = __attribute__((ext_vector_type(4))) float;

__device__ __forceinline__ u16 f2b(float f) {
    union { float f; u32 u; } x; x.f = f;
    u32 u = x.u;
    u32 r = (u + 0x7fffu + ((u >> 16) & 1u)) >> 16;   // RNE
    return (u16)r;
}
__device__ __forceinline__ float b2f(u16 b) {
    union { u32 u; float f; } x; x.u = ((u32)b) << 16;
    return x.f;
}

// ---------------------------------------------------------------------------
// flat fp32 -> bf16 cast (n multiple of 1024)
// ---------------------------------------------------------------------------
__global__ __launch_bounds__(256) void cast_bf16(const float* __restrict__ in,
                                                 u16* __restrict__ out, int n) {
    int i = (blockIdx.x * 256 + threadIdx.x) * 4;
    if (i < n) {
        float4 v = *reinterpret_cast<const float4*>(&in[i]);
        ushort4 o;
        o.x = f2b(v.x); o.y = f2b(v.y); o.z = f2b(v.z); o.w = f2b(v.w);
        *reinterpret_cast<ushort4*>(&out[i]) = o;
    }
}

// ---------------------------------------------------------------------------
// fp32 [R][C] -> bf16 [C][R] transpose-cast. R,C multiples of 32.
// grid (C/32, R/32), block 256.
// ---------------------------------------------------------------------------
__global__ __launch_bounds__(256) void transpose_cast(const float* __restrict__ in,
                                                      u16* __restrict__ out,
                                                      int R, int C) {
    __shared__ float t[32][33];
    const int c0 = blockIdx.x * 32, r0 = blockIdx.y * 32;
    const int tr = threadIdx.x >> 5, tc = threadIdx.x & 31;
    #pragma unroll
    for (int i = 0; i < 4; ++i)
        t[tr + i * 8][tc] = in[(size_t)(r0 + tr + i * 8) * C + c0 + tc];
    __syncthreads();
    #pragma unroll
    for (int i = 0; i < 4; ++i)
        out[(size_t)(c0 + tr + i * 8) * R + r0 + tc] = f2b(t[tc][tr + i * 8]);
}

// ---------------------------------------------------------------------------
// bf16 MFMA GEMM: C[M,N] = A[M,K] (bf16, row) * Bt[N,K]^T (bf16, row).
// 128x128 tile, BK=32, 256 threads (4 waves, each 64x64), 16 MFMAs/wave/step.
// OB: write bf16 (u16) else fp32.
// ---------------------------------------------------------------------------
template<bool OB>
__global__ __launch_bounds__(256) void gemm_bf16(const u16* __restrict__ A,
                                                 const u16* __restrict__ Bt,
                                                 void* __restrict__ Cv,
                                                 int M, int N, int K) {
    __shared__ u16 As[128 * 32];
    __shared__ u16 Bs[128 * 32];
    const int t = threadIdx.x;
    const int w = t >> 6, lane = t & 63, quad = lane >> 4, l15 = lane & 15;
    const int m0 = blockIdx.y * 128, n0 = blockIdx.x * 128;
    const int wr = (w >> 1) * 64, wc = (w & 1) * 64;

    f32x4 acc[4][4];
    #pragma unroll
    for (int mt = 0; mt < 4; ++mt)
        #pragma unroll
        for (int nt = 0; nt < 4; ++nt)
            #pragma unroll
            for (int r = 0; r < 4; ++r) acc[mt][nt][r] = 0.0f;

    for (int k0 = 0; k0 < K; k0 += 32) {
        __syncthreads();
        #pragma unroll
        for (int i = 0; i < 2; ++i) {
            int c = t + i * 256;               // 512 chunks of 8 elems
            int row = c >> 2, kp = (c & 3) * 8;
            *reinterpret_cast<uint4*>(&As[row * 32 + kp]) =
                *reinterpret_cast<const uint4*>(&A[(size_t)(m0 + row) * K + k0 + kp]);
            *reinterpret_cast<uint4*>(&Bs[row * 32 + kp]) =
                *reinterpret_cast<const uint4*>(&Bt[(size_t)(n0 + row) * K + k0 + kp]);
        }
        __syncthreads();

        bf16x8 a[4], b[4];
        #pragma unroll
        for (int mt = 0; mt < 4; ++mt)
            a[mt] = *reinterpret_cast<const bf16x8*>(&As[(wr + mt * 16 + l15) * 32 + quad * 8]);
        #pragma unroll
        for (int nt = 0; nt < 4; ++nt)
            b[nt] = *reinterpret_cast<const bf16x8*>(&Bs[(wc + nt * 16 + l15) * 32 + quad * 8]);
        #pragma unroll
        for (int mt = 0; mt < 4; ++mt)
            #pragma unroll
            for (int nt = 0; nt < 4; ++nt)
                acc[mt][nt] = __builtin_amdgcn_mfma_f32_16x16x32_bf16(a[mt], b[nt], acc[mt][nt], 0, 0, 0);
    }

    #pragma unroll
    for (int mt = 0; mt < 4; ++mt)
        #pragma unroll
        for (int nt = 0; nt < 4; ++nt)
            #pragma unroll
            for (int r = 0; r < 4; ++r) {
                int row = m0 + wr + mt * 16 + quad * 4 + r;
                int col = n0 + wc + nt * 16 + l15;
                float v = acc[mt][nt][r];
                if (OB) ((u16*)Cv)[(size_t)row * N + col] = f2b(v);
                else    ((float*)Cv)[(size_t)row * N + col] = v;
            }
}

// ---------------------------------------------------------------------------
// In-place RMSNorm + RoPE on bf16 Q (32 heads) and K (8 heads).
// grid (SEQLEN, 10), block 256: one wave per (s, head) 64-vector.
// ---------------------------------------------------------------------------
__global__ __launch_bounds__(256) void norm_rope_bf16(u16* __restrict__ Qb,
                                                      u16* __restrict__ Kb,
                                                      const float* __restrict__ cosb,
                                                      const float* __restrict__ sinb,
                                                      const float* __restrict__ qw,
                                                      const float* __restrict__ kw) {
    const int s    = blockIdx.x;
    const int wave = threadIdx.x >> 6;
    const int lane = threadIdx.x & 63;
    const int head = blockIdx.y * 4 + wave;   // 0..39

    u16* base;
    const float* w;
    if (head < NH) { base = Qb + (size_t)s * DQ + head * HD;        w = qw; }
    else           { base = Kb + (size_t)s * DKV + (head - NH) * HD; w = kw; }

    float v  = b2f(base[lane]);
    float ss = v * v;
    #pragma unroll
    for (int off = 32; off; off >>= 1) ss += __shfl_xor(ss, off);
    float r  = rsqrtf(ss * (1.0f / 64.0f) + 1e-6f);
    float vn = v * r * w[lane];

    float partner = __shfl_xor(vn, 32);
    float sgn = (lane < 32) ? -1.0f : 1.0f;
    base[lane] = f2b(vn * cosb[s * HD + lane] + sgn * partner * sinb[s * HD + lane]);
}

// ---------------------------------------------------------------------------
// MFMA flash attention (bf16 in, bf16 out), causal, GQA (4 q-heads / kv-head).
// grid 1D: block b -> h = b&31, qtile = b>>5 (balances causal work per CU).
// 4 waves; wave w owns q-rows [w*16, w*16+16). Online softmax in registers.
// LDS rows padded to 72 elems (144 B) for the conflict-minimal b128 pattern.
// ---------------------------------------------------------------------------
__global__ __launch_bounds__(256) void attn_mfma(const u16* __restrict__ Qb,
                                                 const u16* __restrict__ Kb,
                                                 const u16* __restrict__ VtG,
                                                 u16* __restrict__ attnb) {
    __shared__ u16 Qs[64 * 72];
    __shared__ u16 Ks[64 * 72];
    __shared__ u16 Vt[64 * 72];       // [d][kv] (V transposed)
    __shared__ u16 Ps[4 * 16 * 72];   // per-wave P strip [16][72]

    const int b   = blockIdx.x;
    const int h   = b & 31;
    const int q0  = (b >> 5) * 64;
    const int kvh = h >> 2;
    const int t    = threadIdx.x;
    const int w    = t >> 6, lane = t & 63, quad = lane >> 4, l15 = lane & 15;
    u16* Pw = &Ps[w * 16 * 72];

    // Q tile: [qrow][d]
    #pragma unroll
    for (int i = 0; i < 2; ++i) {
        int c = t + i * 256;
        int row = c >> 3, d8 = (c & 7) * 8;
        *reinterpret_cast<uint4*>(&Qs[row * 72 + d8]) =
            *reinterpret_cast<const uint4*>(&Qb[(size_t)(q0 + row) * DQ + h * HD + d8]);
    }

    f32x4 o[4];
    float mr[4], lr[4];
    #pragma unroll
    for (int nt = 0; nt < 4; ++nt)
        #pragma unroll
        for (int r = 0; r < 4; ++r) o[nt][r] = 0.0f;
    #pragma unroll
    for (int r = 0; r < 4; ++r) { mr[r] = -1e30f; lr[r] = 0.0f; }

    for (int k0 = 0; k0 <= q0; k0 += 64) {
        __syncthreads();   // prev iter done with Ks/Vt
        #pragma unroll
        for (int i = 0; i < 2; ++i) {
            int c = t + i * 256;
            int row = c >> 3, d8 = (c & 7) * 8;
            *reinterpret_cast<uint4*>(&Ks[row * 72 + d8]) =
                *reinterpret_cast<const uint4*>(&Kb[(size_t)(k0 + row) * DKV + kvh * HD + d8]);
            *reinterpret_cast<uint4*>(&Vt[row * 72 + d8]) =
                *reinterpret_cast<const uint4*>(&VtG[(size_t)(kvh * HD + row) * SEQLEN + k0 + d8]);
        }
        __syncthreads();

        // S strip = Q[w*16..+15] . K^T  (64 cols)
        f32x4 s[4];
        #pragma unroll
        for (int nt = 0; nt < 4; ++nt)
            #pragma unroll
            for (int r = 0; r < 4; ++r) s[nt][r] = 0.0f;
        #pragma unroll
        for (int ks = 0; ks < 2; ++ks) {
            bf16x8 qa = *reinterpret_cast<const bf16x8*>(&Qs[(w * 16 + l15) * 72 + ks * 32 + quad * 8]);
            #pragma unroll
            for (int nt = 0; nt < 4; ++nt) {
                bf16x8 kb = *reinterpret_cast<const bf16x8*>(&Ks[(nt * 16 + l15) * 72 + ks * 32 + quad * 8]);
                s[nt] = __builtin_amdgcn_mfma_f32_16x16x32_bf16(qa, kb, s[nt], 0, 0, 0);
            }
        }

        const bool diag = (k0 == q0);
        float pv[4][4];   // [nt][reg]
        float alpha[4];
        #pragma unroll
        for (int r = 0; r < 4; ++r) {
            float mx = -1e30f;
            #pragma unroll
            for (int nt = 0; nt < 4; ++nt) {
                float sc = s[nt][r] * 0.125f;
                if (diag && (nt * 16 + l15) > (w * 16 + quad * 4 + r)) sc = -1e30f;
                pv[nt][r] = sc;
                mx = fmaxf(mx, sc);
            }
            #pragma unroll
            for (int off = 1; off < 16; off <<= 1) mx = fmaxf(mx, __shfl_xor(mx, off));
            float mnew = fmaxf(mr[r], mx);
            alpha[r] = __expf(mr[r] - mnew);
            float ps = 0.0f;
            #pragma unroll
            for (int nt = 0; nt < 4; ++nt) {
                float p = __expf(pv[nt][r] - mnew);
                pv[nt][r] = p;
                ps += p;
            }
            #pragma unroll
            for (int off = 1; off < 16; off <<= 1) ps += __shfl_xor(ps, off);
            lr[r] = lr[r] * alpha[r] + ps;
            mr[r] = mnew;
        }

        // P strip -> LDS (C-layout -> A-layout round trip, wave-private)
        #pragma unroll
        for (int nt = 0; nt < 4; ++nt)
            #pragma unroll
            for (int r = 0; r < 4; ++r)
                Pw[(quad * 4 + r) * 72 + nt * 16 + l15] = f2b(pv[nt][r]);

        #pragma unroll
        for (int nt = 0; nt < 4; ++nt)
            #pragma unroll
            for (int r = 0; r < 4; ++r) o[nt][r] *= alpha[r];

        // O += P . V   (A = P strip, B = Vt)
        #pragma unroll
        for (int ks = 0; ks < 2; ++ks) {
            bf16x8 pa = *reinterpret_cast<const bf16x8*>(&Pw[l15 * 72 + ks * 32 + quad * 8]);
            #pragma unroll
            for (int nt = 0; nt < 4; ++nt) {
                bf16x8 vb = *reinterpret_cast<const bf16x8*>(&Vt[(nt * 16 + l15) * 72 + ks * 32 + quad * 8]);
                o[nt] = __builtin_amdgcn_mfma_f32_16x16x32_bf16(pa, vb, o[nt], 0, 0, 0);
            }
        }
    }

    #pragma unroll
    for (int nt = 0; nt < 4; ++nt)
        #pragma unroll
        for (int r = 0; r < 4; ++r) {
            int row = q0 + w * 16 + quad * 4 + r;
            int col = h * HD + nt * 16 + l15;
            attnb[(size_t)row * DQ + col] = f2b(o[nt][r] / lr[r]);
        }
}

// ---------------------------------------------------------------------------
extern "C" void kernel_launch(void* const* d_in, const int* in_sizes, int n_in,
                              void* d_out, int out_size, void* d_ws, size_t ws_size,
                              hipStream_t stream) {
    const float* x    = (const float*)d_in[0];
    const float* cosb = (const float*)d_in[1];
    const float* sinb = (const float*)d_in[2];
    const float* wq   = (const float*)d_in[3];
    const float* wk   = (const float*)d_in[4];
    const float* wv   = (const float*)d_in[5];
    const float* wo   = (const float*)d_in[6];
    const float* qnw  = (const float*)d_in[7];
    const float* knw  = (const float*)d_in[8];
    float* out = (float*)d_out;

    char* ws = (char*)d_ws;
    const size_t MB = 1024 * 1024;
    u16*   xb    = (u16*)(ws + 0);          // 8MB ; VtG aliases here after xb dead
    u16*   wqT   = (u16*)(ws + 8  * MB);    // 8MB
    u16*   wkT   = (u16*)(ws + 16 * MB);    // 2MB
    u16*   wvT   = (u16*)(ws + 18 * MB);    // 2MB
    u16*   woT   = (u16*)(ws + 20 * MB);    // 8MB
    u16*   Qb    = (u16*)(ws + 28 * MB);    // 8MB
    u16*   Kb    = (u16*)(ws + 36 * MB);    // 2MB
    u16*   attnb = (u16*)(ws + 38 * MB);    // 8MB ; first 4MB doubles as Vf
    float* Vf    = (float*)(ws + 38 * MB);  // 4MB fp32 V (dead after transpose)
    u16*   VtG   = (u16*)(ws + 0);          // 2MB, aliases xb (xb dead by then)

    // 1) casts / weight transposes
    cast_bf16<<<(SEQLEN * DIN) / 1024, 256, 0, stream>>>(x, xb, SEQLEN * DIN);
    transpose_cast<<<dim3(DQ / 32,  DIN / 32), 256, 0, stream>>>(wq, wqT, DIN, DQ);
    transpose_cast<<<dim3(DKV / 32, DIN / 32), 256, 0, stream>>>(wk, wkT, DIN, DKV);
    transpose_cast<<<dim3(DKV / 32, DIN / 32), 256, 0, stream>>>(wv, wvT, DIN, DKV);
    transpose_cast<<<dim3(DIN / 32, DQ / 32),  256, 0, stream>>>(wo, woT, DQ, DIN);

    // 2) projections (bf16 MFMA)
    gemm_bf16<true ><<<dim3(DQ / 128,  SEQLEN / 128), 256, 0, stream>>>(xb, wqT, Qb, SEQLEN, DQ,  DIN);
    gemm_bf16<true ><<<dim3(DKV / 128, SEQLEN / 128), 256, 0, stream>>>(xb, wkT, Kb, SEQLEN, DKV, DIN);
    gemm_bf16<false><<<dim3(DKV / 128, SEQLEN / 128), 256, 0, stream>>>(xb, wvT, Vf, SEQLEN, DKV, DIN);

    // 3) V -> V^T bf16 (for PV B-fragments); xb is dead from here on
    transpose_cast<<<dim3(DKV / 32, SEQLEN / 32), 256, 0, stream>>>(Vf, VtG, SEQLEN, DKV);

    // 4) RMSNorm + RoPE in place on bf16 Q/K
    norm_rope_bf16<<<dim3(SEQLEN, 10), 256, 0, stream>>>(Qb, Kb, cosb, sinb, qnw, knw);

    // 5) causal GQA flash attention (MFMA)
    attn_mfma<<<(SEQLEN / 64) * NH, 256, 0, stream>>>(Qb, Kb, VtG, attnb);

    // 6) output projection
    gemm_bf16<false><<<dim3(DIN / 128, SEQLEN / 128), 256, 0, stream>>>(attnb, woT, out, SEQLEN, DIN, DQ);
}

// Round 3
// 327.589 us; speedup vs baseline: 9.7850x; 1.2560x over previous
//
#include <hip/hip_runtime.h>
#include <math.h>

#define SEQLEN 2048
#define DIN 2048
#define NH 32
#define NKV 8
#define HD 64
#define DQ (NH*HD)    // 2048
#define DKV (NKV*HD)  // 512

using u16 = unsigned short;
using u32 = unsigned int;
using bf16x8 = __attribute__((ext_vector_type(8))) __bf16;
using f32x4  = __attribute__((ext_vector_type(4))) float;

__device__ __forceinline__ u16 f2b(float f) {
    union { float f; u32 u; } x; x.f = f;
    u32 u = x.u;
    u32 r = (u + 0x7fffu + ((u >> 16) & 1u)) >> 16;   // RNE
    return (u16)r;
}
__device__ __forceinline__ float b2f(u16 b) {
    union { u32 u; float f; } x; x.u = ((u32)b) << 16;
    return x.f;
}

// async global->LDS, 16B per lane; lds dst must be wave-uniform base.
__device__ __forceinline__ void gl2lds16(const u16* g, u16* l) {
    __builtin_amdgcn_global_load_lds(
        (const __attribute__((address_space(1))) void*)g,
        (__attribute__((address_space(3))) void*)l,
        16, 0, 0);
}

// ---------------------------------------------------------------------------
// flat fp32 -> bf16 cast (n multiple of 1024)
// ---------------------------------------------------------------------------
__global__ __launch_bounds__(256) void cast_bf16(const float* __restrict__ in,
                                                 u16* __restrict__ out, int n) {
    int i = (blockIdx.x * 256 + threadIdx.x) * 4;
    if (i < n) {
        float4 v = *reinterpret_cast<const float4*>(&in[i]);
        ushort4 o;
        o.x = f2b(v.x); o.y = f2b(v.y); o.z = f2b(v.z); o.w = f2b(v.w);
        *reinterpret_cast<ushort4*>(&out[i]) = o;
    }
}

// ---------------------------------------------------------------------------
// fp32 [R][C] -> bf16 [C][R] transpose-cast. R,C multiples of 32.
// ---------------------------------------------------------------------------
__global__ __launch_bounds__(256) void transpose_cast(const float* __restrict__ in,
                                                      u16* __restrict__ out,
                                                      int R, int C) {
    __shared__ float t[32][33];
    const int c0 = blockIdx.x * 32, r0 = blockIdx.y * 32;
    const int tr = threadIdx.x >> 5, tc = threadIdx.x & 31;
    #pragma unroll
    for (int i = 0; i < 4; ++i)
        t[tr + i * 8][tc] = in[(size_t)(r0 + tr + i * 8) * C + c0 + tc];
    __syncthreads();
    #pragma unroll
    for (int i = 0; i < 4; ++i)
        out[(size_t)(c0 + tr + i * 8) * R + r0 + tc] = f2b(t[tc][tr + i * 8]);
}

// ---------------------------------------------------------------------------
// bf16 MFMA GEMM, m97-style: 128x128 tile, BK=32, global_load_lds staging.
// A[M][K] bf16 row-major, Bt[N][K] bf16 row-major (= B^T).
// MODE 0: C fp32 [M][N].  MODE 1: QKV routing epilogue:
//   col <2048 -> Qb bf16 [M][2048]; col<2560 -> Kb bf16 [M][512];
//   else V written TRANSPOSED: VtG bf16 [512][M].
// ---------------------------------------------------------------------------
template<int MODE>
__global__ __launch_bounds__(256) void gemm_glds(const u16* __restrict__ A,
                                                 const u16* __restrict__ Bt,
                                                 float* __restrict__ Cf,
                                                 u16* __restrict__ Qb,
                                                 u16* __restrict__ Kb,
                                                 u16* __restrict__ VtG,
                                                 int M, int N, int K) {
    __shared__ u16 As[128 * 32];
    __shared__ u16 Bs[128 * 32];
    const int t = threadIdx.x;
    const int w = t >> 6, lane = t & 63, quad = lane >> 4, l15 = lane & 15;
    const int m0 = blockIdx.y * 128, n0 = blockIdx.x * 128;
    const int wr = (w >> 1) * 64, wc = (w & 1) * 64;
    const int srow = lane >> 2;          // 0..15 within chunk
    const int skp  = (lane & 3) * 8;     // k offset within row

    f32x4 acc[4][4];
    #pragma unroll
    for (int mt = 0; mt < 4; ++mt)
        #pragma unroll
        for (int nt = 0; nt < 4; ++nt)
            #pragma unroll
            for (int r = 0; r < 4; ++r) acc[mt][nt][r] = 0.0f;

    for (int k0 = 0; k0 < K; k0 += 32) {
        __syncthreads();
        #pragma unroll
        for (int i = 0; i < 2; ++i) {
            int c = w * 2 + i;           // 0..7, chunk = 16 rows x 32 k
            int row = c * 16 + srow;
            gl2lds16(A  + (size_t)(m0 + row) * K + k0 + skp, As + c * 512);
            gl2lds16(Bt + (size_t)(n0 + row) * K + k0 + skp, Bs + c * 512);
        }
        __syncthreads();

        bf16x8 a[4], b[4];
        #pragma unroll
        for (int mt = 0; mt < 4; ++mt)
            a[mt] = *reinterpret_cast<const bf16x8*>(&As[(wr + mt * 16 + l15) * 32 + quad * 8]);
        #pragma unroll
        for (int nt = 0; nt < 4; ++nt)
            b[nt] = *reinterpret_cast<const bf16x8*>(&Bs[(wc + nt * 16 + l15) * 32 + quad * 8]);
        #pragma unroll
        for (int mt = 0; mt < 4; ++mt)
            #pragma unroll
            for (int nt = 0; nt < 4; ++nt)
                acc[mt][nt] = __builtin_amdgcn_mfma_f32_16x16x32_bf16(a[mt], b[nt], acc[mt][nt], 0, 0, 0);
    }

    #pragma unroll
    for (int mt = 0; mt < 4; ++mt)
        #pragma unroll
        for (int nt = 0; nt < 4; ++nt)
            #pragma unroll
            for (int r = 0; r < 4; ++r) {
                int row = m0 + wr + mt * 16 + quad * 4 + r;
                int col = n0 + wc + nt * 16 + l15;
                float v = acc[mt][nt][r];
                if (MODE == 0) {
                    Cf[(size_t)row * N + col] = v;
                } else {
                    if (col < 2048)      Qb[(size_t)row * 2048 + col] = f2b(v);
                    else if (col < 2560) Kb[(size_t)row * 512 + (col - 2048)] = f2b(v);
                    else                 VtG[(size_t)(col - 2560) * 2048 + row] = f2b(v);
                }
            }
}

// ---------------------------------------------------------------------------
// In-place RMSNorm + RoPE on bf16 Q (32 heads, pre-scaled by 0.125*log2e)
// and K (8 heads). grid (SEQLEN, 10), block 256.
// ---------------------------------------------------------------------------
__global__ __launch_bounds__(256) void norm_rope_bf16(u16* __restrict__ Qb,
                                                      u16* __restrict__ Kb,
                                                      const float* __restrict__ cosb,
                                                      const float* __restrict__ sinb,
                                                      const float* __restrict__ qw,
                                                      const float* __restrict__ kw) {
    const int s    = blockIdx.x;
    const int wave = threadIdx.x >> 6;
    const int lane = threadIdx.x & 63;
    const int head = blockIdx.y * 4 + wave;   // 0..39

    u16* base;
    const float* w;
    if (head < NH) { base = Qb + (size_t)s * DQ + head * HD;         w = qw; }
    else           { base = Kb + (size_t)s * DKV + (head - NH) * HD; w = kw; }

    float v  = b2f(base[lane]);
    float ss = v * v;
    #pragma unroll
    for (int off = 32; off; off >>= 1) ss += __shfl_xor(ss, off);
    float r  = rsqrtf(ss * (1.0f / 64.0f) + 1e-6f);
    float vn = v * r * w[lane];

    float partner = __shfl_xor(vn, 32);
    float sgn = (lane < 32) ? -1.0f : 1.0f;
    float res = vn * cosb[s * HD + lane] + sgn * partner * sinb[s * HD + lane];
    if (head < NH) res *= 0.18033688f;   // 0.125 * log2(e): scores in exp2 domain
    base[lane] = f2b(res);
}

// ---------------------------------------------------------------------------
// MFMA flash attention v2: transposed-score scheme, fixed-shift softmax.
//   S^T = K . Q^T         (C-layout: q = lane&15, kv = quad*4+r)
//   p   = exp2(s2 - 24)   (Q pre-scaled; shift-invariant, no running max)
//   O^T += V^T . P^T      (P^T C-layout IS the B-frag under virtual-K remap:
//                          k_virt = quad*8+j -> kv = quad*4+j for j<4, 0 pad)
// No P LDS round-trip, no in-loop shuffles. l accumulates per-lane; 2
// shuffles at the end. K/V staged via global_load_lds in [2][64][32] halves.
// grid: 1024 blocks; h = b&31, qtile = 31-(b>>5) (heavy blocks first).
// ---------------------------------------------------------------------------
__global__ __launch_bounds__(256) void attn_mfma2(const u16* __restrict__ Qb,
                                                  const u16* __restrict__ Kb,
                                                  const u16* __restrict__ VtG,
                                                  u16* __restrict__ attnb) {
    __shared__ u16 Ks[2 * 64 * 32];   // [d-half][kv 0..63][d 0..31]
    __shared__ u16 Vt[2 * 64 * 32];   // [kv-half][d 0..63][kv 0..31]

    const int b    = blockIdx.x;
    const int h    = b & 31;
    const int qt   = 31 - (b >> 5);
    const int q0   = qt * 64;
    const int kvh  = h >> 2;
    const int t    = threadIdx.x;
    const int w    = t >> 6, lane = t & 63, quad = lane >> 4, l15 = lane & 15;
    const int srow = lane >> 2, skp = (lane & 3) * 8;

    // Hoisted Q B-frags straight from global: q = q0 + w*16 + l15.
    const u16* qrow = Qb + (size_t)(q0 + w * 16 + l15) * DQ + h * HD;
    bf16x8 qB[2];
    qB[0] = *reinterpret_cast<const bf16x8*>(qrow + quad * 8);
    qB[1] = *reinterpret_cast<const bf16x8*>(qrow + 32 + quad * 8);

    f32x4 o[4];                        // O^T: d = dt*16+quad*4+r, q = w*16+l15
    #pragma unroll
    for (int dt = 0; dt < 4; ++dt)
        #pragma unroll
        for (int r = 0; r < 4; ++r) o[dt][r] = 0.0f;
    float lpart = 0.0f;

    for (int k0 = 0; k0 <= q0; k0 += 64) {
        __syncthreads();
        #pragma unroll
        for (int i = 0; i < 2; ++i) {
            int c = w * 2 + i;                       // 0..7
            int hh = c >> 2, cc = c & 3;
            gl2lds16(Kb + (size_t)(k0 + cc * 16 + srow) * DKV + kvh * HD + hh * 32 + skp,
                     Ks + c * 512);
            gl2lds16(VtG + (size_t)(kvh * HD + cc * 16 + srow) * 2048 + k0 + hh * 32 + skp,
                     Vt + c * 512);
        }
        __syncthreads();

        // S^T = K.Q^T : 4 kv-tiles x 2 d-steps
        f32x4 s[4];
        #pragma unroll
        for (int kt = 0; kt < 4; ++kt)
            #pragma unroll
            for (int r = 0; r < 4; ++r) s[kt][r] = 0.0f;
        #pragma unroll
        for (int ks = 0; ks < 2; ++ks)
            #pragma unroll
            for (int kt = 0; kt < 4; ++kt) {
                bf16x8 ka = *reinterpret_cast<const bf16x8*>(
                    &Ks[ks * 2048 + (kt * 16 + l15) * 32 + quad * 8]);
                s[kt] = __builtin_amdgcn_mfma_f32_16x16x32_bf16(ka, qB[ks], s[kt], 0, 0, 0);
            }

        const bool diag = (k0 == q0);
        u32 pb[4][2];
        #pragma unroll
        for (int kt = 0; kt < 4; ++kt) {
            float p[4];
            #pragma unroll
            for (int r = 0; r < 4; ++r) {
                float sv = s[kt][r];
                if (diag && (kt * 16 + quad * 4 + r) > (w * 16 + l15)) sv = -1e30f;
                p[r] = exp2f(sv - 24.0f);
                lpart += p[r];
            }
            pb[kt][0] = ((u32)f2b(p[1]) << 16) | f2b(p[0]);
            pb[kt][1] = ((u32)f2b(p[3]) << 16) | f2b(p[2]);
        }

        // O^T += V^T.P^T  (zero-padded virtual K=32)
        #pragma unroll
        for (int kt = 0; kt < 4; ++kt) {
            union { bf16x8 v; u32 u[4]; } pu;
            pu.u[0] = pb[kt][0]; pu.u[1] = pb[kt][1]; pu.u[2] = 0; pu.u[3] = 0;
            #pragma unroll
            for (int dt = 0; dt < 4; ++dt) {
                union { bf16x8 v; u32 u[4]; } va;
                const u16* vp = &Vt[(kt >> 1) * 2048 + (dt * 16 + l15) * 32 +
                                    (kt & 1) * 16 + quad * 4];
                uint2 vv = *reinterpret_cast<const uint2*>(vp);
                va.u[0] = vv.x; va.u[1] = vv.y; va.u[2] = 0; va.u[3] = 0;
                o[dt] = __builtin_amdgcn_mfma_f32_16x16x32_bf16(va.v, pu.v, o[dt], 0, 0, 0);
            }
        }
    }

    lpart += __shfl_xor(lpart, 16);
    lpart += __shfl_xor(lpart, 32);
    float inv = 1.0f / lpart;

    #pragma unroll
    for (int dt = 0; dt < 4; ++dt) {
        ushort4 ov;
        ov.x = f2b(o[dt][0] * inv);
        ov.y = f2b(o[dt][1] * inv);
        ov.z = f2b(o[dt][2] * inv);
        ov.w = f2b(o[dt][3] * inv);
        *reinterpret_cast<ushort4*>(attnb + (size_t)(q0 + w * 16 + l15) * DQ +
                                    h * HD + dt * 16 + quad * 4) = ov;
    }
}

// ---------------------------------------------------------------------------
extern "C" void kernel_launch(void* const* d_in, const int* in_sizes, int n_in,
                              void* d_out, int out_size, void* d_ws, size_t ws_size,
                              hipStream_t stream) {
    const float* x    = (const float*)d_in[0];
    const float* cosb = (const float*)d_in[1];
    const float* sinb = (const float*)d_in[2];
    const float* wq   = (const float*)d_in[3];
    const float* wk   = (const float*)d_in[4];
    const float* wv   = (const float*)d_in[5];
    const float* wo   = (const float*)d_in[6];
    const float* qnw  = (const float*)d_in[7];
    const float* knw  = (const float*)d_in[8];
    float* out = (float*)d_out;

    char* ws = (char*)d_ws;
    const size_t MB = 1024 * 1024;
    u16* xb     = (u16*)(ws + 0);         // 8 MB
    u16* wqkvT  = (u16*)(ws + 8  * MB);   // 12 MB: [wq^T; wk^T; wv^T] = [3072][2048]
    u16* woT    = (u16*)(ws + 20 * MB);   // 8 MB
    u16* Qb     = (u16*)(ws + 28 * MB);   // 8 MB
    u16* Kb     = (u16*)(ws + 36 * MB);   // 2 MB
    u16* VtG    = (u16*)(ws + 38 * MB);   // 2 MB  [512][2048]
    u16* attnb  = (u16*)(ws + 40 * MB);   // 8 MB

    // 1) prep: cast x, transpose-cast weights (wq/wk/wv contiguous -> QKV weight)
    cast_bf16<<<(SEQLEN * DIN) / 1024, 256, 0, stream>>>(x, xb, SEQLEN * DIN);
    transpose_cast<<<dim3(DQ / 32,  DIN / 32), 256, 0, stream>>>(wq, wqkvT, DIN, DQ);
    transpose_cast<<<dim3(DKV / 32, DIN / 32), 256, 0, stream>>>(wk, wqkvT + (size_t)2048 * 2048, DIN, DKV);
    transpose_cast<<<dim3(DKV / 32, DIN / 32), 256, 0, stream>>>(wv, wqkvT + (size_t)2560 * 2048, DIN, DKV);
    transpose_cast<<<dim3(DIN / 32, DQ / 32),  256, 0, stream>>>(wo, woT, DQ, DIN);

    // 2) fused QKV projection (V written transposed in epilogue)
    gemm_glds<1><<<dim3(3072 / 128, SEQLEN / 128), 256, 0, stream>>>(
        xb, wqkvT, nullptr, Qb, Kb, VtG, SEQLEN, 3072, DIN);

    // 3) RMSNorm + RoPE (Q pre-scaled into exp2 domain)
    norm_rope_bf16<<<dim3(SEQLEN, 10), 256, 0, stream>>>(Qb, Kb, cosb, sinb, qnw, knw);

    // 4) causal GQA flash attention v2
    attn_mfma2<<<(SEQLEN / 64) * NH, 256, 0, stream>>>(Qb, Kb, VtG, attnb);

    // 5) output projection
    gemm_glds<0><<<dim3(DIN / 128, SEQLEN / 128), 256, 0, stream>>>(
        attnb, woT, out, nullptr, nullptr, nullptr, SEQLEN, DIN, DQ);
}